// Round 3
// baseline (303.159 us; speedup 1.0000x reference)
//
#include <hip/hip_runtime.h>

// Flash-attention fwd, B=2,S=2048,H=16,D=128, logits = QK^T / D.
// Round 10: fix R9's failing cross-group combine. Per-wave compute is the
// R8-verified code (64 q-rows/wave, P in registers via permlane32_swap,
// 0.5 LDS b128 reads per MFMA). KV split across two 256-thread wave groups
// (group g processes contiguous tiles g*16..g*16+15) to reach 8 waves/CU
// (2/SIMD) -- the q dimension alone only fills 1024 of 2048 wave slots.
// R9's epilogue used runtime-indexed o4[][giv+dk] (rule-#20 scratch path)
// and f32x16 LDS stores at 16B-aligned addresses (UB): R10 epilogue is
// fully static (literal tile indices per group branch) and exchanges
// partials via float4 only. LDS = 143,360 B, 1 block/CU, 8 waves.

#define SEQ   2048
#define NHEAD 16
#define DH    128
#define NB    2
#define BQ    256
#define BK    64
#define NTHR  512
#define KSTR  136   // ushorts; 272B row
#define VSTR  72    // ushorts; 144B row
#define NKV   (SEQ / BK)
#define NIT   (NKV / 2)
#define NELEM (NB * SEQ * NHEAD * DH)
#define KTILE (BK * KSTR)   // 8704 ushorts
#define VTILE (DH * VSTR)   // 9216 ushorts

typedef __attribute__((ext_vector_type(8)))  short bf16x8;
typedef __attribute__((ext_vector_type(16))) float f32x16;
typedef __attribute__((ext_vector_type(4)))  unsigned int u32x4;

__device__ __forceinline__ unsigned short f2bf(float x) {
    unsigned int u = __builtin_bit_cast(unsigned int, x);
    u += 0x7fffu + ((u >> 16) & 1u);
    return (unsigned short)(u >> 16);
}

// two f32 -> packed bf16 dword (truncate; same P rounding as R7/R8)
__device__ __forceinline__ unsigned int pk2bf(float lo, float hi) {
    return (__builtin_bit_cast(unsigned int, hi) & 0xffff0000u)
         | (__builtin_bit_cast(unsigned int, lo) >> 16);
}

// exchange: a.hi32lanes <-> b.lo32lanes  (v_permlane32_swap_b32)
__device__ __forceinline__ void pl32(unsigned int& a, unsigned int& b) {
    asm("v_permlane32_swap_b32 %0, %1" : "+v"(a), "+v"(b));
}

// ---- pass 1: fp32 -> bf16 (RNE); Q additionally scaled by log2(e)/D
__global__ __launch_bounds__(256) void cvt_bf16(
    const float* __restrict__ q, const float* __restrict__ k,
    const float* __restrict__ v, unsigned short* __restrict__ dst)
{
    const int y = blockIdx.y;
    const float* s = (y == 0) ? q : (y == 1) ? k : v;
    const float scl = (y == 0) ? (1.44269504088896340736f / 128.0f) : 1.0f;
    unsigned short* d = dst + (size_t)y * NELEM;
    const int i = blockIdx.x * 256 + threadIdx.x;
    const float4 x = ((const float4*)s)[i];
    ushort4 o;
    o.x = f2bf(x.x * scl); o.y = f2bf(x.y * scl);
    o.z = f2bf(x.z * scl); o.w = f2bf(x.w * scl);
    ((ushort4*)d)[i] = o;
}

// ---- pass 2: attention
__global__ __launch_bounds__(NTHR, 2) void attn_fwd(
    const unsigned short* __restrict__ Qb,
    const unsigned short* __restrict__ Kb,
    const unsigned short* __restrict__ Vb,
    float* __restrict__ O)
{
    // [4 K buffers][4 V buffers]; group g uses K/V buffers {2g, 2g+1}.
    __shared__ unsigned short Sm[4 * KTILE + 4 * VTILE];   // 143,360 B

    const int tid   = threadIdx.x;
    const int gt    = tid & 255;   // thread id within group
    const int group = tid >> 8;    // 0: tiles 0..15, 1: tiles 16..31
    const int wave  = tid >> 6;
    const int wv    = wave & 3;    // wave within group
    const int lane  = tid & 63;
    const int hx    = lane >> 5;   // 0/1
    const int l32   = lane & 31;

    const int b  = blockIdx.y >> 4;
    const int h  = blockIdx.y & 15;
    const int q0 = blockIdx.x * BQ;

    const size_t rs = (size_t)NHEAD * DH;   // 2048 elems between seq rows
    const unsigned short* qb = Qb + (size_t)b * SEQ * rs + (size_t)h * DH;
    const unsigned short* kb = Kb + (size_t)b * SEQ * rs + (size_t)h * DH;
    const unsigned short* vb = Vb + (size_t)b * SEQ * rs + (size_t)h * DH;

    // ---- Q as B-operand frags for 2 q-subtiles: B[k=d][n=q], n=l32,
    // k=(lane>>5)*8+j (+c*16). Q is pre-scaled by log2(e)/D.
    bf16x8 qf[2][8];
    #pragma unroll
    for (int qt = 0; qt < 2; ++qt) {
        const unsigned short* qp =
            qb + (size_t)(q0 + wv * 64 + qt * 32 + l32) * rs + hx * 8;
        #pragma unroll
        for (int c = 0; c < 8; ++c)
            qf[qt][c] = *(const bf16x8*)(qp + c * 16);
    }

    // ---- staging maps (per 256-thread group; same as R8)
    int kgo[4], kls[4];   // K: 1024 16B-chunks: key=cidx>>4, cc=cidx&15
    #pragma unroll
    for (int p = 0; p < 4; ++p) {
        const int cidx = (wv * 4 + p) * 64 + lane;
        const int key  = cidx >> 4;
        const int cc   = cidx & 15;
        kgo[p] = key * (int)rs + cc * 8;
        kls[p] = key * KSTR + cc * 8;
    }
    const int kp  = gt & 31;   // V: key-pair index
    const int dcv = gt >> 5;   // V: d-chunk 0..7 (+8 on p=1)

    f32x16 o4[2][4];
    #pragma unroll
    for (int qt = 0; qt < 2; ++qt)
        #pragma unroll
        for (int t = 0; t < 4; ++t)
            #pragma unroll
            for (int r = 0; r < 16; ++r) o4[qt][t][r] = 0.f;
    float lsum[2] = {0.f, 0.f};

    bf16x8 kr[4], vr[4];
    const int t0 = group * NIT;   // first tile for this group

    // prologue: group g stages tile t0 into its buffer 0
    {
        const size_t kbase = (size_t)(t0 * BK) * rs;
        #pragma unroll
        for (int p = 0; p < 4; ++p) kr[p] = *(const bf16x8*)(kb + kbase + kgo[p]);
        #pragma unroll
        for (int p = 0; p < 2; ++p) {
            const unsigned short* src =
                vb + (size_t)(t0 * BK + 2 * kp) * rs + (dcv + p * 8) * 8;
            vr[p * 2]     = *(const bf16x8*)src;
            vr[p * 2 + 1] = *(const bf16x8*)(src + rs);
        }
        unsigned short* Kw = &Sm[(2 * group + 0) * KTILE];
        #pragma unroll
        for (int p = 0; p < 4; ++p) *(bf16x8*)&Kw[kls[p]] = kr[p];
        unsigned int* vw = (unsigned int*)&Sm[4 * KTILE + (2 * group + 0) * VTILE];
        #pragma unroll
        for (int p = 0; p < 2; ++p)
            #pragma unroll
            for (int j = 0; j < 8; ++j) {
                const unsigned int pr = ((unsigned int)(unsigned short)vr[p * 2][j])
                                      | (((unsigned int)(unsigned short)vr[p * 2 + 1][j]) << 16);
                vw[((dcv + p * 8) * 8 + j) * (VSTR / 2) + kp] = pr;
            }
    }
    __syncthreads();

    for (int it = 0; it < NIT; ++it) {
        const int cur   = it & 1;
        const bool last = (it == NIT - 1);
        const int k0n   = (t0 + it + 1) * BK;   // next tile base row

        // ---- issue next tile's global loads (consumed after compute)
        if (!last) {
            #pragma unroll
            for (int p = 0; p < 4; ++p)
                kr[p] = *(const bf16x8*)(kb + (size_t)k0n * rs + kgo[p]);
            #pragma unroll
            for (int p = 0; p < 2; ++p) {
                const unsigned short* src =
                    vb + (size_t)(k0n + 2 * kp) * rs + (dcv + p * 8) * 8;
                vr[p * 2]     = *(const bf16x8*)src;
                vr[p * 2 + 1] = *(const bf16x8*)(src + rs);
            }
        }

        const unsigned short* Kc = &Sm[(2 * group + cur) * KTILE];
        const unsigned short* Vc = &Sm[4 * KTILE + (2 * group + cur) * VTILE];

        #pragma unroll
        for (int kt = 0; kt < 2; ++kt) {
            // ---- S^T(32 keys x 32 q) = K * Q^T, both q-subtiles;
            // each kf read feeds 2 MFMAs.
            f32x16 s[2];
            #pragma unroll
            for (int r = 0; r < 16; ++r) { s[0][r] = 0.f; s[1][r] = 0.f; }
            #pragma unroll
            for (int c = 0; c < 8; ++c) {
                bf16x8 kf = *(const bf16x8*)&Kc[(kt * 32 + l32) * KSTR + c * 16 + hx * 8];
                s[0] = __builtin_amdgcn_mfma_f32_32x32x16_bf16(kf, qf[0][c], s[0], 0, 0, 0);
                s[1] = __builtin_amdgcn_mfma_f32_32x32x16_bf16(kf, qf[1][c], s[1], 0, 0, 0);
            }

            // ---- exp2 (arg pre-scaled via Q) + pack to bf16 dwords.
            // lane holds P[q=l32][key=(r&3)+8*(r>>2)+4*hx]; w[g][p] =
            // keys (8g+4hx+2p, +1).
            unsigned int w[2][4][2];
            #pragma unroll
            for (int qt = 0; qt < 2; ++qt)
                #pragma unroll
                for (int g = 0; g < 4; ++g) {
                    const float e0 = __builtin_amdgcn_exp2f(s[qt][g * 4 + 0]);
                    const float e1 = __builtin_amdgcn_exp2f(s[qt][g * 4 + 1]);
                    const float e2 = __builtin_amdgcn_exp2f(s[qt][g * 4 + 2]);
                    const float e3 = __builtin_amdgcn_exp2f(s[qt][g * 4 + 3]);
                    lsum[qt] += (e0 + e1) + (e2 + e3);
                    w[qt][g][0] = pk2bf(e0, e1);
                    w[qt][g][1] = pk2bf(e2, e3);
                }

            // ---- lane l <-> l+32 half-exchange -> PV A-frags in registers
            #pragma unroll
            for (int qt = 0; qt < 2; ++qt)
                #pragma unroll
                for (int ks = 0; ks < 2; ++ks) {
                    pl32(w[qt][2 * ks][0], w[qt][2 * ks + 1][0]);
                    pl32(w[qt][2 * ks][1], w[qt][2 * ks + 1][1]);
                }
            bf16x8 pf[2][2];
            #pragma unroll
            for (int qt = 0; qt < 2; ++qt)
                #pragma unroll
                for (int ks = 0; ks < 2; ++ks) {
                    u32x4 t;
                    t.x = w[qt][2 * ks][0];
                    t.y = w[qt][2 * ks][1];
                    t.z = w[qt][2 * ks + 1][0];
                    t.w = w[qt][2 * ks + 1][1];
                    pf[qt][ks] = __builtin_bit_cast(bf16x8, t);
                }

            // ---- O += P V; each vf read feeds 2 MFMAs (both q-subtiles)
            #pragma unroll
            for (int ks = 0; ks < 2; ++ks)
                #pragma unroll
                for (int dt = 0; dt < 4; ++dt) {
                    bf16x8 vf = *(const bf16x8*)&Vc[(dt * 32 + l32) * VSTR
                                                    + kt * 32 + ks * 16 + hx * 8];
                    o4[0][dt] = __builtin_amdgcn_mfma_f32_32x32x16_bf16(pf[0][ks], vf, o4[0][dt], 0, 0, 0);
                    o4[1][dt] = __builtin_amdgcn_mfma_f32_32x32x16_bf16(pf[1][ks], vf, o4[1][dt], 0, 0, 0);
                }
        }

        // ---- write staged next tile into the other buffer
        if (!last) {
            const int nxt = cur ^ 1;
            unsigned short* Kw = &Sm[(2 * group + nxt) * KTILE];
            #pragma unroll
            for (int p = 0; p < 4; ++p) *(bf16x8*)&Kw[kls[p]] = kr[p];
            unsigned int* vw = (unsigned int*)&Sm[4 * KTILE + (2 * group + nxt) * VTILE];
            #pragma unroll
            for (int p = 0; p < 2; ++p)
                #pragma unroll
                for (int j = 0; j < 8; ++j) {
                    const unsigned int pr = ((unsigned int)(unsigned short)vr[p * 2][j])
                                          | (((unsigned int)(unsigned short)vr[p * 2 + 1][j]) << 16);
                    vw[((dcv + p * 8) * 8 + j) * (VSTR / 2) + kp] = pr;
                }
        }
        __syncthreads();
    }

    // ---- epilogue: cross-group combine via LDS. All o4 indices are
    // LITERAL (static) -- no scratch; exchange uses float4 only (regions
    // are 272 B apart -> every float4 address is 16B-aligned).
    float lsc[2];
    #pragma unroll
    for (int qt = 0; qt < 2; ++qt) {
        float ls = lsum[qt];
        ls += __shfl_xor(ls, 32, 64);   // combine the two key-halves (hx)
        lsc[qt] = ls;
    }

    float* Ep = (float*)Sm;
    float* mine = Ep + (size_t)((group << 8) + gt) * 68;

    // donate the d-tiles the peer will store: g0 -> {2,3}, g1 -> {0,1}
    if (group == 0) {
        #pragma unroll
        for (int j = 0; j < 4; ++j) {
            float4 a, bq, c, d;
            a.x  = o4[0][2][4*j+0]; a.y  = o4[0][2][4*j+1]; a.z  = o4[0][2][4*j+2]; a.w  = o4[0][2][4*j+3];
            bq.x = o4[0][3][4*j+0]; bq.y = o4[0][3][4*j+1]; bq.z = o4[0][3][4*j+2]; bq.w = o4[0][3][4*j+3];
            c.x  = o4[1][2][4*j+0]; c.y  = o4[1][2][4*j+1]; c.z  = o4[1][2][4*j+2]; c.w  = o4[1][2][4*j+3];
            d.x  = o4[1][3][4*j+0]; d.y  = o4[1][3][4*j+1]; d.z  = o4[1][3][4*j+2]; d.w  = o4[1][3][4*j+3];
            *(float4*)&mine[ 0 + 4*j] = a;
            *(float4*)&mine[16 + 4*j] = bq;
            *(float4*)&mine[32 + 4*j] = c;
            *(float4*)&mine[48 + 4*j] = d;
        }
    } else {
        #pragma unroll
        for (int j = 0; j < 4; ++j) {
            float4 a, bq, c, d;
            a.x  = o4[0][0][4*j+0]; a.y  = o4[0][0][4*j+1]; a.z  = o4[0][0][4*j+2]; a.w  = o4[0][0][4*j+3];
            bq.x = o4[0][1][4*j+0]; bq.y = o4[0][1][4*j+1]; bq.z = o4[0][1][4*j+2]; bq.w = o4[0][1][4*j+3];
            c.x  = o4[1][0][4*j+0]; c.y  = o4[1][0][4*j+1]; c.z  = o4[1][0][4*j+2]; c.w  = o4[1][0][4*j+3];
            d.x  = o4[1][1][4*j+0]; d.y  = o4[1][1][4*j+1]; d.z  = o4[1][1][4*j+2]; d.w  = o4[1][1][4*j+3];
            *(float4*)&mine[ 0 + 4*j] = a;
            *(float4*)&mine[16 + 4*j] = bq;
            *(float4*)&mine[32 + 4*j] = c;
            *(float4*)&mine[48 + 4*j] = d;
        }
    }
    mine[64] = lsc[0];
    mine[65] = lsc[1];
    __syncthreads();

    const float* peer = Ep + (size_t)(((1 - group) << 8) + gt) * 68;
    #pragma unroll
    for (int qt = 0; qt < 2; ++qt) {
        const float lt  = lsc[qt] + peer[64 + qt];
        const float inv = 1.0f / lt;     // valid for q = l32 (both halves)
        float iv[16];
        #pragma unroll
        for (int r = 0; r < 16; ++r)
            iv[r] = __shfl(inv, (r & 3) + 8 * (r >> 2) + 4 * hx, 64);

        if (group == 0) {
            #pragma unroll
            for (int r = 0; r < 16; ++r) {
                const int ql = (r & 3) + 8 * (r >> 2) + 4 * hx;
                float* orow = O + (size_t)(b * SEQ + q0 + wv * 64 + qt * 32 + ql) * rs
                                + (size_t)h * DH + l32;
                orow[ 0] = (o4[qt][0][r] + peer[(qt * 2 + 0) * 16 + r]) * iv[r];
                orow[32] = (o4[qt][1][r] + peer[(qt * 2 + 1) * 16 + r]) * iv[r];
            }
        } else {
            #pragma unroll
            for (int r = 0; r < 16; ++r) {
                const int ql = (r & 3) + 8 * (r >> 2) + 4 * hx;
                float* orow = O + (size_t)(b * SEQ + q0 + wv * 64 + qt * 32 + ql) * rs
                                + (size_t)h * DH + l32;
                orow[64] = (o4[qt][2][r] + peer[(qt * 2 + 0) * 16 + r]) * iv[r];
                orow[96] = (o4[qt][3][r] + peer[(qt * 2 + 1) * 16 + r]) * iv[r];
            }
        }
    }
}

extern "C" void kernel_launch(void* const* d_in, const int* in_sizes, int n_in,
                              void* d_out, int out_size, void* d_ws, size_t ws_size,
                              hipStream_t stream) {
    const float* q = (const float*)d_in[0];
    const float* k = (const float*)d_in[1];
    const float* v = (const float*)d_in[2];
    float* o = (float*)d_out;
    unsigned short* wsb = (unsigned short*)d_ws;

    cvt_bf16<<<dim3(NELEM / 1024, 3), 256, 0, stream>>>(q, k, v, wsb);
    attn_fwd<<<dim3(SEQ / BQ, NB * NHEAD), dim3(NTHR), 0, stream>>>(
        wsb, wsb + NELEM, wsb + 2 * (size_t)NELEM, o);
}

// Round 5
// 214.149 us; speedup vs baseline: 1.4156x; 1.4156x over previous
//
#include <hip/hip_runtime.h>

// Flash-attention fwd, B=2,S=2048,H=16,D=128, logits = QK^T / D.
// Round 12: numerics-hardened R11. R11 (32q/wave + permlane P path) failed
// absmax at 2.93e-3 vs 1.83e-3 -- an accumulation-precision failure, not a
// race (indexing bugs give O(1) errors). Root systematic error: O uses
// bf16-TRUNCATED P (one-sided bias -2^-9) while L summed full-fp32 e ->
// O/L biased ~2e-3 relative. Fixes:
//  (1) CONSISTENT O/L: round e to bf16 (half-up) once; accumulate the
//      rounded value into lsum AND pack the same bits into P. Bias cancels
//      exactly in the O/L ratio.
//  (2) half-up rounding (symmetric +-2^-9) instead of truncation (-2^-8).
//  (3) Q-scale fold reverted: c1=log2e/128 applied post-MFMA in fp32,
//      exactly as the twice-verified R7 path.
// Structure unchanged from R11: BQ=128, 4 waves x 32 q-rows, P in registers
// via v_permlane32_swap, double-buffered K/V, LDS=71,680B -> 2 blocks/CU,
// 8 waves/CU (2/SIMD).

#define SEQ   2048
#define NHEAD 16
#define DH    128
#define NB    2
#define BQ    128
#define BK    64
#define NTHR  256
#define KSTR  136   // ushorts; 272B row; conflict-free for 32-lane frag reads
#define VSTR  72    // ushorts; 144B row
#define NKV   (SEQ / BK)
#define NELEM (NB * SEQ * NHEAD * DH)
#define KTILE (BK * KSTR)   // 8704 ushorts
#define VTILE (DH * VSTR)   // 9216 ushorts

typedef __attribute__((ext_vector_type(8)))  short bf16x8;
typedef __attribute__((ext_vector_type(16))) float f32x16;
typedef __attribute__((ext_vector_type(4)))  unsigned int u32x4;

__device__ __forceinline__ unsigned short f2bf(float x) {
    unsigned int u = __builtin_bit_cast(unsigned int, x);
    u += 0x7fffu + ((u >> 16) & 1u);
    return (unsigned short)(u >> 16);
}

// round-half-up to bf16; returns the bf16 value's fp32 bit pattern
__device__ __forceinline__ unsigned int bfr(float x) {
    unsigned int u = __builtin_bit_cast(unsigned int, x);
    return (u + 0x8000u) & 0xffff0000u;
}

// exchange: a.hi32lanes <-> b.lo32lanes  (v_permlane32_swap_b32)
__device__ __forceinline__ void pl32(unsigned int& a, unsigned int& b) {
    asm("v_permlane32_swap_b32 %0, %1" : "+v"(a), "+v"(b));
}

// ---- pass 1: fp32 -> bf16 (RNE), memory-bound
__global__ __launch_bounds__(256) void cvt_bf16(
    const float* __restrict__ q, const float* __restrict__ k,
    const float* __restrict__ v, unsigned short* __restrict__ dst)
{
    const int y = blockIdx.y;
    const float* s = (y == 0) ? q : (y == 1) ? k : v;
    unsigned short* d = dst + (size_t)y * NELEM;
    const int i = blockIdx.x * 256 + threadIdx.x;
    const float4 x = ((const float4*)s)[i];
    ushort4 o;
    o.x = f2bf(x.x); o.y = f2bf(x.y); o.z = f2bf(x.z); o.w = f2bf(x.w);
    ((ushort4*)d)[i] = o;
}

// ---- pass 2: attention
__global__ __launch_bounds__(NTHR, 2) void attn_fwd(
    const unsigned short* __restrict__ Qb,
    const unsigned short* __restrict__ Kb,
    const unsigned short* __restrict__ Vb,
    float* __restrict__ O)
{
    __shared__ unsigned short Kl[2][KTILE];   // 2 x 17,408 B
    __shared__ unsigned short Vl[2][VTILE];   // 2 x 18,432 B  [d][k]

    const int tid  = threadIdx.x;
    const int wave = tid >> 6;
    const int lane = tid & 63;
    const int hx   = lane >> 5;   // 0/1
    const int l32  = lane & 31;

    const int b  = blockIdx.y >> 4;
    const int h  = blockIdx.y & 15;
    const int q0 = blockIdx.x * BQ;

    const size_t rs = (size_t)NHEAD * DH;   // 2048 elems between seq rows
    const unsigned short* qb = Qb + (size_t)b * SEQ * rs + (size_t)h * DH;
    const unsigned short* kb = Kb + (size_t)b * SEQ * rs + (size_t)h * DH;
    const unsigned short* vb = Vb + (size_t)b * SEQ * rs + (size_t)h * DH;

    // ---- Q as B-operand frags: B[k=d][n=q], n=l32, k=(lane>>5)*8+j (+c*16)
    bf16x8 qf[8];
    {
        const unsigned short* qp = qb + (size_t)(q0 + wave * 32 + l32) * rs + hx * 8;
        #pragma unroll
        for (int c = 0; c < 8; ++c)
            qf[c] = *(const bf16x8*)(qp + c * 16);
    }

    // ---- staging maps (256 threads; same as R7/R8)
    int kgo[4], kls[4];   // K: 1024 16B-chunks: key=cidx>>4, cc=cidx&15
    #pragma unroll
    for (int p = 0; p < 4; ++p) {
        const int cidx = (wave * 4 + p) * 64 + lane;
        const int key  = cidx >> 4;
        const int cc   = cidx & 15;
        kgo[p] = key * (int)rs + cc * 8;
        kls[p] = key * KSTR + cc * 8;
    }
    const int kp  = tid & 31;   // V: key-pair index
    const int dcv = tid >> 5;   // V: d-chunk 0..7 (+8 on p=1)

    f32x16 o4[4];
    #pragma unroll
    for (int t = 0; t < 4; ++t)
        #pragma unroll
        for (int r = 0; r < 16; ++r) o4[t][r] = 0.f;
    float lsum = 0.f;
    const float c1 = 1.44269504088896340736f / 128.0f;  // log2(e)/D

    bf16x8 kr[4], vr[4];

    // prologue: stage tile 0 into buffer 0
    {
        #pragma unroll
        for (int p = 0; p < 4; ++p) kr[p] = *(const bf16x8*)(kb + kgo[p]);
        #pragma unroll
        for (int p = 0; p < 2; ++p) {
            const unsigned short* src = vb + (size_t)(2 * kp) * rs + (dcv + p * 8) * 8;
            vr[p * 2]     = *(const bf16x8*)src;
            vr[p * 2 + 1] = *(const bf16x8*)(src + rs);
        }
        #pragma unroll
        for (int p = 0; p < 4; ++p) *(bf16x8*)&Kl[0][kls[p]] = kr[p];
        unsigned int* vw = (unsigned int*)&Vl[0][0];
        #pragma unroll
        for (int p = 0; p < 2; ++p)
            #pragma unroll
            for (int j = 0; j < 8; ++j) {
                const unsigned int pr = ((unsigned int)(unsigned short)vr[p * 2][j])
                                      | (((unsigned int)(unsigned short)vr[p * 2 + 1][j]) << 16);
                vw[((dcv + p * 8) * 8 + j) * (VSTR / 2) + kp] = pr;
            }
    }
    __syncthreads();

    for (int kv = 0; kv < NKV; ++kv) {
        const int cur = kv & 1;
        const int k0n = ((kv + 1) & (NKV - 1)) * BK;

        // ---- issue next tile's global loads (consumed after compute)
        #pragma unroll
        for (int p = 0; p < 4; ++p) kr[p] = *(const bf16x8*)(kb + (size_t)k0n * rs + kgo[p]);
        #pragma unroll
        for (int p = 0; p < 2; ++p) {
            const unsigned short* src = vb + (size_t)(k0n + 2 * kp) * rs + (dcv + p * 8) * 8;
            vr[p * 2]     = *(const bf16x8*)src;
            vr[p * 2 + 1] = *(const bf16x8*)(src + rs);
        }

        const unsigned short* Kc = &Kl[cur][0];
        const unsigned short* Vc = &Vl[cur][0];

        #pragma unroll
        for (int kt = 0; kt < 2; ++kt) {
            // ---- S^T(32 keys x 32 q) = K * Q^T
            f32x16 s;
            #pragma unroll
            for (int r = 0; r < 16; ++r) s[r] = 0.f;
            #pragma unroll
            for (int c = 0; c < 8; ++c) {
                bf16x8 kf = *(const bf16x8*)&Kc[(kt * 32 + l32) * KSTR + c * 16 + hx * 8];
                s = __builtin_amdgcn_mfma_f32_32x32x16_bf16(kf, qf[c], s, 0, 0, 0);
            }

            // ---- exp2(s*c1), round to bf16 ONCE; lsum accumulates the
            // ROUNDED values (O/L consistency -- truncation bias cancels).
            // lane holds P[q=l32][key=(r&3)+8*(r>>2)+4*hx]; w[g][p] =
            // keys (8g+4hx+2p, +1).
            unsigned int w[4][2];
            #pragma unroll
            for (int g = 0; g < 4; ++g) {
                const unsigned int u0 = bfr(__builtin_amdgcn_exp2f(s[g * 4 + 0] * c1));
                const unsigned int u1 = bfr(__builtin_amdgcn_exp2f(s[g * 4 + 1] * c1));
                const unsigned int u2 = bfr(__builtin_amdgcn_exp2f(s[g * 4 + 2] * c1));
                const unsigned int u3 = bfr(__builtin_amdgcn_exp2f(s[g * 4 + 3] * c1));
                lsum += (__builtin_bit_cast(float, u0) + __builtin_bit_cast(float, u1))
                      + (__builtin_bit_cast(float, u2) + __builtin_bit_cast(float, u3));
                w[g][0] = u1 | (u0 >> 16);
                w[g][1] = u3 | (u2 >> 16);
            }

            // ---- lane l <-> l+32 half-exchange -> PV A-frags in registers
            #pragma unroll
            for (int ks = 0; ks < 2; ++ks) {
                pl32(w[2 * ks][0], w[2 * ks + 1][0]);
                pl32(w[2 * ks][1], w[2 * ks + 1][1]);
            }
            bf16x8 pf[2];
            #pragma unroll
            for (int ks = 0; ks < 2; ++ks) {
                u32x4 t;
                t.x = w[2 * ks][0];
                t.y = w[2 * ks][1];
                t.z = w[2 * ks + 1][0];
                t.w = w[2 * ks + 1][1];
                pf[ks] = __builtin_bit_cast(bf16x8, t);
            }

            // ---- O += P V for this key-tile (wave-private, no barrier)
            #pragma unroll
            for (int ks = 0; ks < 2; ++ks)
                #pragma unroll
                for (int dt = 0; dt < 4; ++dt) {
                    bf16x8 vf = *(const bf16x8*)&Vc[(dt * 32 + l32) * VSTR
                                                    + kt * 32 + ks * 16 + hx * 8];
                    o4[dt] = __builtin_amdgcn_mfma_f32_32x32x16_bf16(pf[ks], vf, o4[dt], 0, 0, 0);
                }
        }

        // ---- write staged next tile into the other buffer
        const int nxt = cur ^ 1;
        #pragma unroll
        for (int p = 0; p < 4; ++p) *(bf16x8*)&Kl[nxt][kls[p]] = kr[p];
        {
            unsigned int* vw = (unsigned int*)&Vl[nxt][0];
            #pragma unroll
            for (int p = 0; p < 2; ++p)
                #pragma unroll
                for (int j = 0; j < 8; ++j) {
                    const unsigned int pr = ((unsigned int)(unsigned short)vr[p * 2][j])
                                          | (((unsigned int)(unsigned short)vr[p * 2 + 1][j]) << 16);
                    vw[((dcv + p * 8) * 8 + j) * (VSTR / 2) + kp] = pr;
                }
        }
        __syncthreads();
    }

    // ---- epilogue: L per q, then normalize + store (coalesced 128B runs)
    lsum += __shfl_xor(lsum, 32, 64);
    const float inv = 1.0f / lsum;     // valid for q = l32 (both halves)
    float iv[16];
    #pragma unroll
    for (int r = 0; r < 16; ++r)
        iv[r] = __shfl(inv, (r & 3) + 8 * (r >> 2) + 4 * hx, 64);

    #pragma unroll
    for (int dt = 0; dt < 4; ++dt) {
        #pragma unroll
        for (int r = 0; r < 16; ++r) {
            const int ql = (r & 3) + 8 * (r >> 2) + 4 * hx;
            const int qg = q0 + wave * 32 + ql;
            O[(size_t)(b * SEQ + qg) * rs + (size_t)h * DH + dt * 32 + l32] = o4[dt][r] * iv[r];
        }
    }
}

extern "C" void kernel_launch(void* const* d_in, const int* in_sizes, int n_in,
                              void* d_out, int out_size, void* d_ws, size_t ws_size,
                              hipStream_t stream) {
    const float* q = (const float*)d_in[0];
    const float* k = (const float*)d_in[1];
    const float* v = (const float*)d_in[2];
    float* o = (float*)d_out;
    unsigned short* wsb = (unsigned short*)d_ws;

    cvt_bf16<<<dim3(NELEM / 1024, 3), 256, 0, stream>>>(q, k, v, wsb);
    attn_fwd<<<dim3(SEQ / BQ, NB * NHEAD), dim3(NTHR), 0, stream>>>(
        wsb, wsb + NELEM, wsb + 2 * (size_t)NELEM, o);
}

// Round 6
// 208.920 us; speedup vs baseline: 1.4511x; 1.0250x over previous
//
#include <hip/hip_runtime.h>

// Flash-attention fwd, B=2,S=2048,H=16,D=128, logits = QK^T / D.
// Round 13: staging-dedup round. R12 budget decomposition (per CU per iter,
// 6830 cyc): LDS ~3800 (56%, reads 3072 + duplicated staging stores), VALU
// 38%, MFMA 2066 (30% -- matches MfmaUtil at the 8.07 cyc/MFMA/CU chip
// rate). The two independent blocks/CU each staged their own 32KB/iter.
// Fix: ONE 512-thread block (8 waves x 32 q-rows, BQ=256) so a single
// staging stream serves all 8 waves: staging LDS stores, staging VALU and
// K/V global fetch per CU all halve. Occupancy unchanged (8 waves/CU =
// 2/SIMD; per-thread regs ~192 unified < 256 cap via launch_bounds(512,2)).
// Per-wave compute/numerics BYTE-IDENTICAL to passing R12 (bfr half-up
// rounding, consistent O/L, c1 post-MFMA). Grid 8x32 = 256 blocks = 1/CU.

#define SEQ   2048
#define NHEAD 16
#define DH    128
#define NB    2
#define BQ    256
#define BK    64
#define NTHR  512
#define KSTR  136   // ushorts; 272B row; conflict-free for 32-lane frag reads
#define VSTR  72    // ushorts; 144B row
#define NKV   (SEQ / BK)
#define NELEM (NB * SEQ * NHEAD * DH)
#define KTILE (BK * KSTR)   // 8704 ushorts
#define VTILE (DH * VSTR)   // 9216 ushorts

typedef __attribute__((ext_vector_type(8)))  short bf16x8;
typedef __attribute__((ext_vector_type(16))) float f32x16;
typedef __attribute__((ext_vector_type(4)))  unsigned int u32x4;

__device__ __forceinline__ unsigned short f2bf(float x) {
    unsigned int u = __builtin_bit_cast(unsigned int, x);
    u += 0x7fffu + ((u >> 16) & 1u);
    return (unsigned short)(u >> 16);
}

// round-half-up to bf16; returns the bf16 value's fp32 bit pattern
__device__ __forceinline__ unsigned int bfr(float x) {
    unsigned int u = __builtin_bit_cast(unsigned int, x);
    return (u + 0x8000u) & 0xffff0000u;
}

// exchange: a.hi32lanes <-> b.lo32lanes  (v_permlane32_swap_b32)
__device__ __forceinline__ void pl32(unsigned int& a, unsigned int& b) {
    asm("v_permlane32_swap_b32 %0, %1" : "+v"(a), "+v"(b));
}

// ---- pass 1: fp32 -> bf16 (RNE), memory-bound
__global__ __launch_bounds__(256) void cvt_bf16(
    const float* __restrict__ q, const float* __restrict__ k,
    const float* __restrict__ v, unsigned short* __restrict__ dst)
{
    const int y = blockIdx.y;
    const float* s = (y == 0) ? q : (y == 1) ? k : v;
    unsigned short* d = dst + (size_t)y * NELEM;
    const int i = blockIdx.x * 256 + threadIdx.x;
    const float4 x = ((const float4*)s)[i];
    ushort4 o;
    o.x = f2bf(x.x); o.y = f2bf(x.y); o.z = f2bf(x.z); o.w = f2bf(x.w);
    ((ushort4*)d)[i] = o;
}

// ---- pass 2: attention
__global__ __launch_bounds__(NTHR, 2) void attn_fwd(
    const unsigned short* __restrict__ Qb,
    const unsigned short* __restrict__ Kb,
    const unsigned short* __restrict__ Vb,
    float* __restrict__ O)
{
    __shared__ unsigned short Kl[2][KTILE];   // 2 x 17,408 B
    __shared__ unsigned short Vl[2][VTILE];   // 2 x 18,432 B  [d][k]

    const int tid  = threadIdx.x;
    const int wave = tid >> 6;    // 0..7
    const int lane = tid & 63;
    const int hx   = lane >> 5;   // 0/1
    const int l32  = lane & 31;

    const int b  = blockIdx.y >> 4;
    const int h  = blockIdx.y & 15;
    const int q0 = blockIdx.x * BQ;

    const size_t rs = (size_t)NHEAD * DH;   // 2048 elems between seq rows
    const unsigned short* qb = Qb + (size_t)b * SEQ * rs + (size_t)h * DH;
    const unsigned short* kb = Kb + (size_t)b * SEQ * rs + (size_t)h * DH;
    const unsigned short* vb = Vb + (size_t)b * SEQ * rs + (size_t)h * DH;

    // ---- Q as B-operand frags: B[k=d][n=q], n=l32, k=(lane>>5)*8+j (+c*16)
    bf16x8 qf[8];
    {
        const unsigned short* qp = qb + (size_t)(q0 + wave * 32 + l32) * rs + hx * 8;
        #pragma unroll
        for (int c = 0; c < 8; ++c)
            qf[c] = *(const bf16x8*)(qp + c * 16);
    }

    // ---- staging maps (512 threads -> HALF the per-thread work of R12)
    // K: 1024 16B-chunks (64 keys x 16 chunks): 2 per thread, coalesced.
    int kgo[2], kls[2];
    #pragma unroll
    for (int p = 0; p < 2; ++p) {
        const int cidx = p * NTHR + tid;
        const int key  = cidx >> 4;
        const int cc   = cidx & 15;
        kgo[p] = key * (int)rs + cc * 8;
        kls[p] = key * KSTR + cc * 8;
    }
    // V: key-pair kp (0..31) x d-chunk dcv (0..15): 1 (pair, chunk) per thread.
    const int kp  = tid & 31;
    const int dcv = tid >> 5;   // 0..15

    f32x16 o4[4];
    #pragma unroll
    for (int t = 0; t < 4; ++t)
        #pragma unroll
        for (int r = 0; r < 16; ++r) o4[t][r] = 0.f;
    float lsum = 0.f;
    const float c1 = 1.44269504088896340736f / 128.0f;  // log2(e)/D

    bf16x8 kr[2], vr[2];

    // prologue: stage tile 0 into buffer 0
    {
        #pragma unroll
        for (int p = 0; p < 2; ++p) kr[p] = *(const bf16x8*)(kb + kgo[p]);
        {
            const unsigned short* src = vb + (size_t)(2 * kp) * rs + dcv * 8;
            vr[0] = *(const bf16x8*)src;
            vr[1] = *(const bf16x8*)(src + rs);
        }
        #pragma unroll
        for (int p = 0; p < 2; ++p) *(bf16x8*)&Kl[0][kls[p]] = kr[p];
        unsigned int* vw = (unsigned int*)&Vl[0][0];
        #pragma unroll
        for (int j = 0; j < 8; ++j) {
            const unsigned int pr = ((unsigned int)(unsigned short)vr[0][j])
                                  | (((unsigned int)(unsigned short)vr[1][j]) << 16);
            vw[(dcv * 8 + j) * (VSTR / 2) + kp] = pr;
        }
    }
    __syncthreads();

    for (int kv = 0; kv < NKV; ++kv) {
        const int cur = kv & 1;
        const int k0n = ((kv + 1) & (NKV - 1)) * BK;

        // ---- issue next tile's global loads (consumed after compute)
        #pragma unroll
        for (int p = 0; p < 2; ++p) kr[p] = *(const bf16x8*)(kb + (size_t)k0n * rs + kgo[p]);
        {
            const unsigned short* src = vb + (size_t)(k0n + 2 * kp) * rs + dcv * 8;
            vr[0] = *(const bf16x8*)src;
            vr[1] = *(const bf16x8*)(src + rs);
        }

        const unsigned short* Kc = &Kl[cur][0];
        const unsigned short* Vc = &Vl[cur][0];

        #pragma unroll
        for (int kt = 0; kt < 2; ++kt) {
            // ---- S^T(32 keys x 32 q) = K * Q^T
            f32x16 s;
            #pragma unroll
            for (int r = 0; r < 16; ++r) s[r] = 0.f;
            #pragma unroll
            for (int c = 0; c < 8; ++c) {
                bf16x8 kf = *(const bf16x8*)&Kc[(kt * 32 + l32) * KSTR + c * 16 + hx * 8];
                s = __builtin_amdgcn_mfma_f32_32x32x16_bf16(kf, qf[c], s, 0, 0, 0);
            }

            // ---- exp2(s*c1), round to bf16 ONCE; lsum accumulates the
            // ROUNDED values (O/L consistency). lane holds
            // P[q=l32][key=(r&3)+8*(r>>2)+4*hx]; w[g][p]=keys(8g+4hx+2p,+1).
            unsigned int w[4][2];
            #pragma unroll
            for (int g = 0; g < 4; ++g) {
                const unsigned int u0 = bfr(__builtin_amdgcn_exp2f(s[g * 4 + 0] * c1));
                const unsigned int u1 = bfr(__builtin_amdgcn_exp2f(s[g * 4 + 1] * c1));
                const unsigned int u2 = bfr(__builtin_amdgcn_exp2f(s[g * 4 + 2] * c1));
                const unsigned int u3 = bfr(__builtin_amdgcn_exp2f(s[g * 4 + 3] * c1));
                lsum += (__builtin_bit_cast(float, u0) + __builtin_bit_cast(float, u1))
                      + (__builtin_bit_cast(float, u2) + __builtin_bit_cast(float, u3));
                w[g][0] = u1 | (u0 >> 16);
                w[g][1] = u3 | (u2 >> 16);
            }

            // ---- lane l <-> l+32 half-exchange -> PV A-frags in registers
            #pragma unroll
            for (int ks = 0; ks < 2; ++ks) {
                pl32(w[2 * ks][0], w[2 * ks + 1][0]);
                pl32(w[2 * ks][1], w[2 * ks + 1][1]);
            }
            bf16x8 pf[2];
            #pragma unroll
            for (int ks = 0; ks < 2; ++ks) {
                u32x4 t;
                t.x = w[2 * ks][0];
                t.y = w[2 * ks][1];
                t.z = w[2 * ks + 1][0];
                t.w = w[2 * ks + 1][1];
                pf[ks] = __builtin_bit_cast(bf16x8, t);
            }

            // ---- O += P V for this key-tile (wave-private, no barrier)
            #pragma unroll
            for (int ks = 0; ks < 2; ++ks)
                #pragma unroll
                for (int dt = 0; dt < 4; ++dt) {
                    bf16x8 vf = *(const bf16x8*)&Vc[(dt * 32 + l32) * VSTR
                                                    + kt * 32 + ks * 16 + hx * 8];
                    o4[dt] = __builtin_amdgcn_mfma_f32_32x32x16_bf16(pf[ks], vf, o4[dt], 0, 0, 0);
                }
        }

        // ---- write staged next tile into the other buffer
        const int nxt = cur ^ 1;
        #pragma unroll
        for (int p = 0; p < 2; ++p) *(bf16x8*)&Kl[nxt][kls[p]] = kr[p];
        {
            unsigned int* vw = (unsigned int*)&Vl[nxt][0];
            #pragma unroll
            for (int j = 0; j < 8; ++j) {
                const unsigned int pr = ((unsigned int)(unsigned short)vr[0][j])
                                      | (((unsigned int)(unsigned short)vr[1][j]) << 16);
                vw[(dcv * 8 + j) * (VSTR / 2) + kp] = pr;
            }
        }
        __syncthreads();
    }

    // ---- epilogue: L per q, then normalize + store (coalesced 128B runs)
    lsum += __shfl_xor(lsum, 32, 64);
    const float inv = 1.0f / lsum;     // valid for q = l32 (both halves)
    float iv[16];
    #pragma unroll
    for (int r = 0; r < 16; ++r)
        iv[r] = __shfl(inv, (r & 3) + 8 * (r >> 2) + 4 * hx, 64);

    #pragma unroll
    for (int dt = 0; dt < 4; ++dt) {
        #pragma unroll
        for (int r = 0; r < 16; ++r) {
            const int ql = (r & 3) + 8 * (r >> 2) + 4 * hx;
            const int qg = q0 + wave * 32 + ql;
            O[(size_t)(b * SEQ + qg) * rs + (size_t)h * DH + dt * 32 + l32] = o4[dt][r] * iv[r];
        }
    }
}

extern "C" void kernel_launch(void* const* d_in, const int* in_sizes, int n_in,
                              void* d_out, int out_size, void* d_ws, size_t ws_size,
                              hipStream_t stream) {
    const float* q = (const float*)d_in[0];
    const float* k = (const float*)d_in[1];
    const float* v = (const float*)d_in[2];
    float* o = (float*)d_out;
    unsigned short* wsb = (unsigned short*)d_ws;

    cvt_bf16<<<dim3(NELEM / 1024, 3), 256, 0, stream>>>(q, k, v, wsb);
    attn_fwd<<<dim3(SEQ / BQ, NB * NHEAD), dim3(NTHR), 0, stream>>>(
        wsb, wsb + NELEM, wsb + 2 * (size_t)NELEM, o);
}